// Round 4
// baseline (1398.494 us; speedup 1.0000x reference)
//
#include <hip/hip_runtime.h>
#include <hip/hip_bf16.h>
#include <math.h>

#define NNODES 50000
#define NEDGES 800000
#define NGRAPH 512
#define FIN    256
#define H1     256
#define H2     256
#define H3     512
#define FPOUT  2048

// ---------------- utility kernels ----------------

__global__ __launch_bounds__(256) void zero_i32(int* p, int n) {
    int i = blockIdx.x * 256 + threadIdx.x;
    if (i < n) p[i] = 0;
}

__global__ __launch_bounds__(256) void count_deg(const int* __restrict__ ei, int* __restrict__ degi, int e_total) {
    int e = blockIdx.x * 256 + threadIdx.x;
    if (e >= e_total) return;
    int d = ei[e_total + e];
    atomicAdd(&degi[d], 1);
}

__global__ __launch_bounds__(256) void calc_dis(const int* __restrict__ degi, float* __restrict__ dis, int n) {
    int i = blockIdx.x * 256 + threadIdx.x;
    if (i < n) dis[i] = rsqrtf((float)(degi[i] + 1));   // +1 self loop
}

// inclusive scan per 256-chunk; offs[idx+1] = local inclusive, partials[b] = chunk sum
__global__ __launch_bounds__(256) void scanA(const int* __restrict__ degi, int* __restrict__ offs,
                                             int* __restrict__ partials, int n) {
    __shared__ int sm[256];
    int t = threadIdx.x, idx = blockIdx.x * 256 + t;
    int v = (idx < n) ? degi[idx] : 0;
    sm[t] = v; __syncthreads();
    for (int d = 1; d < 256; d <<= 1) {
        int add = (t >= d) ? sm[t - d] : 0;
        __syncthreads();
        sm[t] += add;
        __syncthreads();
    }
    if (idx < n) offs[idx + 1] = sm[t];
    if (t == 255) partials[blockIdx.x] = sm[255];
}

// exclusive scan of partials (nb <= 256), single block
__global__ __launch_bounds__(256) void scanB(int* __restrict__ partials, int nb) {
    __shared__ int sm[256];
    int t = threadIdx.x;
    int v = (t < nb) ? partials[t] : 0;
    sm[t] = v; __syncthreads();
    for (int d = 1; d < 256; d <<= 1) {
        int add = (t >= d) ? sm[t - d] : 0;
        __syncthreads();
        sm[t] += add;
        __syncthreads();
    }
    if (t < nb) partials[t] = sm[t] - v;   // exclusive
}

__global__ __launch_bounds__(256) void scanC(int* __restrict__ offs, const int* __restrict__ partials, int n) {
    int idx = blockIdx.x * 256 + threadIdx.x;
    if (idx < n) offs[idx + 1] += partials[blockIdx.x];
    if (idx == 0) offs[0] = 0;
}

__global__ __launch_bounds__(256) void copy_i32(const int* __restrict__ a, int* __restrict__ b, int n) {
    int i = blockIdx.x * 256 + threadIdx.x;
    if (i < n) b[i] = a[i];
}

__global__ __launch_bounds__(256) void fill_csr(const int* __restrict__ ei, const float* __restrict__ dis,
                                                int* __restrict__ curs, int* __restrict__ csr_src,
                                                float* __restrict__ csr_w, int e_total) {
    int e = blockIdx.x * 256 + threadIdx.x;
    if (e >= e_total) return;
    int s = ei[e];
    int d = ei[e_total + e];
    int pos = atomicAdd(&curs[d], 1);
    csr_src[pos] = s;
    csr_w[pos] = dis[s] * dis[d];
}

// ---------------- SGEMM: C = A[M,K] @ B[K,N] (+bias, relu) ----------------
// 64x64 tile, BK=16, 256 threads, 4x4 microtile.
__global__ __launch_bounds__(256) void sgemm(const float* __restrict__ A, const float* __restrict__ B,
                                             float* __restrict__ C, const float* __restrict__ bias,
                                             int M, int Nn, int K, int do_relu) {
    __shared__ float As[16][68];   // [k][m], +4 pad
    __shared__ float Bs[16][68];   // [k][n], +4 pad
    int tid = threadIdx.x;
    int tx = tid & 15, ty = tid >> 4;
    int row0 = blockIdx.y * 64, col0 = blockIdx.x * 64;
    int arow = tid >> 2, ac4 = (tid & 3) * 4;
    int brow = tid >> 4, bc4 = (tid & 15) * 4;
    float c[4][4] = {};
    for (int k0 = 0; k0 < K; k0 += 16) {
        float4 av = make_float4(0.f, 0.f, 0.f, 0.f);
        if (row0 + arow < M)
            av = *(const float4*)(A + (size_t)(row0 + arow) * K + k0 + ac4);
        As[ac4 + 0][arow] = av.x;
        As[ac4 + 1][arow] = av.y;
        As[ac4 + 2][arow] = av.z;
        As[ac4 + 3][arow] = av.w;
        float4 bv = *(const float4*)(B + (size_t)(k0 + brow) * Nn + col0 + bc4);
        *(float4*)&Bs[brow][bc4] = bv;
        __syncthreads();
        #pragma unroll
        for (int kk = 0; kk < 16; ++kk) {
            float4 a = *(float4*)&As[kk][ty * 4];
            float4 b = *(float4*)&Bs[kk][tx * 4];
            c[0][0] += a.x * b.x; c[0][1] += a.x * b.y; c[0][2] += a.x * b.z; c[0][3] += a.x * b.w;
            c[1][0] += a.y * b.x; c[1][1] += a.y * b.y; c[1][2] += a.y * b.z; c[1][3] += a.y * b.w;
            c[2][0] += a.z * b.x; c[2][1] += a.z * b.y; c[2][2] += a.z * b.z; c[2][3] += a.z * b.w;
            c[3][0] += a.w * b.x; c[3][1] += a.w * b.y; c[3][2] += a.w * b.z; c[3][3] += a.w * b.w;
        }
        __syncthreads();
    }
    #pragma unroll
    for (int i = 0; i < 4; ++i) {
        int row = row0 + ty * 4 + i;
        if (row >= M) continue;
        #pragma unroll
        for (int j = 0; j < 4; ++j) {
            int col = col0 + tx * 4 + j;
            float v = c[i][j];
            if (bias) v += bias[col];
            if (do_relu) v = v > 0.f ? v : 0.f;
            C[(size_t)row * Nn + col] = v;
        }
    }
}

// ---------------- aggregation v4: feature-chunked, XCD-pinned (F=256) ----------------
// Chunk c = 32 columns [c*32, c*32+32). blockIdx.x % 8 == c pins chunk c to XCD c
// (round-robin block->XCD). Per-XCD gather working set = 50k * 128B = 6.4 MB -> mostly
// L2-resident. Wave = one dst node; lanes 0-31 even edges, 32-63 odd edges; each lane
// reads one float of the 128B line h[s][c*32+col].
template<int F>
__global__ __launch_bounds__(256) void agg_c(const float* __restrict__ h, float* __restrict__ xout,
                                             const float* __restrict__ bias, const float* __restrict__ dis,
                                             const int* __restrict__ offs, const int* __restrict__ csr_src,
                                             const float* __restrict__ csr_w) {
    int bid = blockIdx.x;
    int chunk = bid & 7;
    int dblk = bid >> 3;
    int wave = threadIdx.x >> 6;
    int lane = threadIdx.x & 63;
    int v = dblk * 4 + wave;                 // grid sized so v < NNODES
    int half = lane >> 5;
    int col = chunk * (F / 8) + (lane & 31); // F=256: 32 cols/chunk
    int beg = offs[v], end = offs[v + 1];
    float dv = dis[v];
    float acc = (half == 0) ? h[(size_t)v * F + col] * (dv * dv) : 0.f;
    int i = beg + half;
    // two edges in flight per half
    for (; i + 2 < end; i += 4) {
        int s0 = csr_src[i], s1 = csr_src[i + 2];
        float w0 = csr_w[i], w1 = csr_w[i + 2];
        float g0 = h[(size_t)s0 * F + col];
        float g1 = h[(size_t)s1 * F + col];
        acc += g0 * w0 + g1 * w1;
    }
    for (; i < end; i += 2) {
        int s0 = csr_src[i];
        acc += h[(size_t)s0 * F + col] * csr_w[i];
    }
    acc += __shfl_down(acc, 32, 64);
    if (half == 0) {
        float r = acc + bias[col];
        xout[(size_t)v * F + col] = r > 0.f ? r : 0.f;
    }
}

// ---------------- aggregation v3: one wave per node (kept for F=512) ----------------
template<int F>
__global__ __launch_bounds__(256) void agg_w(const float* __restrict__ h, float* __restrict__ xout,
                                             const float* __restrict__ bias, const float* __restrict__ dis,
                                             const int* __restrict__ offs, const int* __restrict__ csr_src,
                                             const float* __restrict__ csr_w) {
    constexpr int V2 = (F > 256) ? 1 : 0;
    constexpr int UNROLL = V2 ? 4 : 8;
    int wave = threadIdx.x >> 6;
    int lane = threadIdx.x & 63;
    int v = __builtin_amdgcn_readfirstlane(blockIdx.x * 4 + wave);
    if (v >= NNODES) return;
    int beg = __builtin_amdgcn_readfirstlane(offs[v]);
    int end = __builtin_amdgcn_readfirstlane(offs[v + 1]);
    float dv = dis[v];
    float selfw = dv * dv;

    const float4* hv = (const float4*)(h + (size_t)v * F);
    float4 a = hv[lane];
    float4 acc0 = make_float4(a.x * selfw, a.y * selfw, a.z * selfw, a.w * selfw);
    float4 acc1 = make_float4(0.f, 0.f, 0.f, 0.f);
    if (V2) {
        float4 b = hv[lane + 64];
        acc1 = make_float4(b.x * selfw, b.y * selfw, b.z * selfw, b.w * selfw);
    }

    int i = beg;
    for (; i + UNROLL <= end; i += UNROLL) {
        int   s[UNROLL];
        float w[UNROLL];
        #pragma unroll
        for (int u = 0; u < UNROLL; ++u) { s[u] = csr_src[i + u]; w[u] = csr_w[i + u]; }
        float4 g0[UNROLL], g1[V2 ? UNROLL : 1];
        #pragma unroll
        for (int u = 0; u < UNROLL; ++u) {
            const float4* hs = (const float4*)(h + (size_t)s[u] * F);
            g0[u] = hs[lane];
            if (V2) g1[u] = hs[lane + 64];
        }
        #pragma unroll
        for (int u = 0; u < UNROLL; ++u) {
            acc0.x += g0[u].x * w[u]; acc0.y += g0[u].y * w[u];
            acc0.z += g0[u].z * w[u]; acc0.w += g0[u].w * w[u];
            if (V2) {
                acc1.x += g1[u].x * w[u]; acc1.y += g1[u].y * w[u];
                acc1.z += g1[u].z * w[u]; acc1.w += g1[u].w * w[u];
            }
        }
    }
    for (; i + 2 <= end; i += 2) {
        int s0 = csr_src[i], s1 = csr_src[i + 1];
        float w0 = csr_w[i], w1 = csr_w[i + 1];
        const float4* h0 = (const float4*)(h + (size_t)s0 * F);
        const float4* h1 = (const float4*)(h + (size_t)s1 * F);
        float4 x0 = h0[lane], x1 = h1[lane];
        acc0.x += x0.x * w0 + x1.x * w1; acc0.y += x0.y * w0 + x1.y * w1;
        acc0.z += x0.z * w0 + x1.z * w1; acc0.w += x0.w * w0 + x1.w * w1;
        if (V2) {
            float4 y0 = h0[lane + 64], y1 = h1[lane + 64];
            acc1.x += y0.x * w0 + y1.x * w1; acc1.y += y0.y * w0 + y1.y * w1;
            acc1.z += y0.z * w0 + y1.z * w1; acc1.w += y0.w * w0 + y1.w * w1;
        }
    }
    if (i < end) {
        int s0 = csr_src[i];
        float w0 = csr_w[i];
        const float4* h0 = (const float4*)(h + (size_t)s0 * F);
        float4 x0 = h0[lane];
        acc0.x += x0.x * w0; acc0.y += x0.y * w0; acc0.z += x0.z * w0; acc0.w += x0.w * w0;
        if (V2) {
            float4 y0 = h0[lane + 64];
            acc1.x += y0.x * w0; acc1.y += y0.y * w0; acc1.z += y0.z * w0; acc1.w += y0.w * w0;
        }
    }

    const float4* bv = (const float4*)bias;
    float4 bb = bv[lane];
    acc0.x += bb.x; acc0.y += bb.y; acc0.z += bb.z; acc0.w += bb.w;
    acc0.x = acc0.x > 0.f ? acc0.x : 0.f;
    acc0.y = acc0.y > 0.f ? acc0.y : 0.f;
    acc0.z = acc0.z > 0.f ? acc0.z : 0.f;
    acc0.w = acc0.w > 0.f ? acc0.w : 0.f;
    float4* xr = (float4*)(xout + (size_t)v * F);
    xr[lane] = acc0;
    if (V2) {
        float4 b2 = bv[lane + 64];
        acc1.x += b2.x; acc1.y += b2.y; acc1.z += b2.z; acc1.w += b2.w;
        acc1.x = acc1.x > 0.f ? acc1.x : 0.f;
        acc1.y = acc1.y > 0.f ? acc1.y : 0.f;
        acc1.z = acc1.z > 0.f ? acc1.z : 0.f;
        acc1.w = acc1.w > 0.f ? acc1.w : 0.f;
        xr[lane + 64] = acc1;
    }
}

// ---------------- gate: wgate[n] = sigmoid(x[n,:512] . pw + pb) ----------------
__global__ __launch_bounds__(256) void gate(const float* __restrict__ x, const float* __restrict__ pw,
                                            const float* __restrict__ pb, float* __restrict__ wgate, int n) {
    int wid = (blockIdx.x * 256 + threadIdx.x) >> 6;
    int lane = threadIdx.x & 63;
    if (wid >= n) return;
    const float4* xr = (const float4*)(x + (size_t)wid * 512);
    const float4* pwv = (const float4*)pw;
    float4 a = xr[lane], b = pwv[lane];
    float4 a1 = xr[lane + 64], b1 = pwv[lane + 64];
    float acc = a.x * b.x + a.y * b.y + a.z * b.z + a.w * b.w
              + a1.x * b1.x + a1.y * b1.y + a1.z * b1.z + a1.w * b1.w;
    #pragma unroll
    for (int off = 32; off; off >>= 1) acc += __shfl_down(acc, off, 64);
    if (lane == 0) wgate[wid] = 1.f / (1.f + expf(-(acc + pb[0])));
}

// ---------------- pool: pooled[g] = [weighted_sum(512) | max(512)] ----------------
__global__ __launch_bounds__(256) void pool(const float* __restrict__ x, const float* __restrict__ wg,
                                            const int* __restrict__ batch, float* __restrict__ pooled, int n) {
    int g = blockIdx.x;
    int t = threadIdx.x;
    int lo = 0, hi = n;
    while (lo < hi) { int mid = (lo + hi) >> 1; if (batch[mid] < g) lo = mid + 1; else hi = mid; }
    int start = lo;
    hi = n;
    while (lo < hi) { int mid = (lo + hi) >> 1; if (batch[mid] < g + 1) lo = mid + 1; else hi = mid; }
    int end = lo;
    float s0 = 0.f, s1 = 0.f, m0 = -INFINITY, m1 = -INFINITY;
    for (int nn = start; nn < end; ++nn) {
        float wn = wg[nn];
        const float* xr = x + (size_t)nn * 512;
        float v0 = xr[t], v1 = xr[t + 256];
        s0 += v0 * wn; s1 += v1 * wn;
        m0 = fmaxf(m0, v0); m1 = fmaxf(m1, v1);
    }
    if (start >= end) { m0 = 0.f; m1 = 0.f; }
    float* pg = pooled + (size_t)g * 1024;
    pg[t] = s0; pg[t + 256] = s1;
    pg[512 + t] = m0; pg[768 + t] = m1;
}

// ---------------- launch ----------------

extern "C" void kernel_launch(void* const* d_in, const int* in_sizes, int n_in,
                              void* d_out, int out_size, void* d_ws, size_t ws_size,
                              hipStream_t stream) {
    const float* x0    = (const float*)d_in[0];
    const int*   ei    = (const int*)d_in[1];
    const int*   batch = (const int*)d_in[2];
    const float* W1 = (const float*)d_in[3];
    const float* b1 = (const float*)d_in[4];
    const float* W2 = (const float*)d_in[5];
    const float* b2 = (const float*)d_in[6];
    const float* W3 = (const float*)d_in[7];
    const float* b3 = (const float*)d_in[8];
    const float* pw = (const float*)d_in[9];
    const float* pb = (const float*)d_in[10];
    const float* Wo = (const float*)d_in[11];
    const float* bo = (const float*)d_in[12];
    float* out = (float*)d_out;

    // workspace layout (4B words, each region 16B-aligned)
    float* ws = (float*)d_ws;
    size_t off = 0;
    float* bufX = ws + off; off += (size_t)NNODES * 512;
    float* bufH = ws + off; off += (size_t)NNODES * 512;
    float* dis  = ws + off; off += NNODES;
    int*   degi = (int*)(ws + off); off += NNODES;
    int*   offs = (int*)(ws + off); off += (NNODES + 4);     // N+1 rounded
    int*   curs = (int*)(ws + off); off += NNODES;
    int*   csr_src = (int*)(ws + off); off += NEDGES;
    float* csr_w   = ws + off; off += NEDGES;
    float* wgate   = ws + off; off += NNODES;
    float* pooled  = ws + off; off += (size_t)NGRAPH * 1024;
    int*   partials = (int*)(ws + off); off += 256;

    const int NB_N = (NNODES + 255) / 256;   // 196
    const int NB_E = (NEDGES + 255) / 256;
    const int NB_W = (NNODES + 3) / 4;       // one wave per node, 4 waves/block (12500)
    const int NB_C = NB_W * 8;               // chunked: 8 chunks x 12500 dst-blocks

    // CSR build
    zero_i32<<<NB_N, 256, 0, stream>>>(degi, NNODES);
    count_deg<<<NB_E, 256, 0, stream>>>(ei, degi, NEDGES);
    calc_dis<<<NB_N, 256, 0, stream>>>(degi, dis, NNODES);
    scanA<<<NB_N, 256, 0, stream>>>(degi, offs, partials, NNODES);
    scanB<<<1, 256, 0, stream>>>(partials, NB_N);
    scanC<<<NB_N, 256, 0, stream>>>(offs, partials, NNODES);
    copy_i32<<<NB_N, 256, 0, stream>>>(offs, curs, NNODES);
    fill_csr<<<NB_E, 256, 0, stream>>>(ei, dis, curs, csr_src, csr_w, NEDGES);

    // layer 1: h = x0 @ W1 ; x1 = relu(agg(h) + b1)
    {
        dim3 grid(H1 / 64, (NNODES + 63) / 64);
        sgemm<<<grid, 256, 0, stream>>>(x0, W1, bufH, nullptr, NNODES, H1, FIN, 0);
        agg_c<256><<<NB_C, 256, 0, stream>>>(bufH, bufX, b1, dis, offs, csr_src, csr_w);
    }
    // layer 2
    {
        dim3 grid(H2 / 64, (NNODES + 63) / 64);
        sgemm<<<grid, 256, 0, stream>>>(bufX, W2, bufH, nullptr, NNODES, H2, H1, 0);
        agg_c<256><<<NB_C, 256, 0, stream>>>(bufH, bufX, b2, dis, offs, csr_src, csr_w);
    }
    // layer 3
    {
        dim3 grid(H3 / 64, (NNODES + 63) / 64);
        sgemm<<<grid, 256, 0, stream>>>(bufX, W3, bufH, nullptr, NNODES, H3, H2, 0);
        agg_w<512><<<NB_W, 256, 0, stream>>>(bufH, bufX, b3, dis, offs, csr_src, csr_w);
    }
    // gate + pool
    gate<<<(NNODES * 64 + 255) / 256, 256, 0, stream>>>(bufX, pw, pb, wgate, NNODES);
    pool<<<NGRAPH, 256, 0, stream>>>(bufX, wgate, batch, pooled, NNODES);
    // head: out = relu(pooled @ Wo + bo)
    {
        dim3 grid(FPOUT / 64, NGRAPH / 64);
        sgemm<<<grid, 256, 0, stream>>>(pooled, Wo, out, bo, NGRAPH, FPOUT, 2 * H3, 1);
    }
}

// Round 5
// 1061.807 us; speedup vs baseline: 1.3171x; 1.3171x over previous
//
#include <hip/hip_runtime.h>
#include <hip/hip_bf16.h>
#include <math.h>

#define NNODES 50000
#define NEDGES 800000
#define NGRAPH 512
#define FIN    256
#define H1     256
#define H2     256
#define H3     512
#define FPOUT  2048

// ---------------- utility kernels ----------------

__global__ __launch_bounds__(256) void zero_i32(int* p, int n) {
    int i = blockIdx.x * 256 + threadIdx.x;
    if (i < n) p[i] = 0;
}

__global__ __launch_bounds__(256) void count_deg(const int* __restrict__ ei, int* __restrict__ degi, int e_total) {
    int e = blockIdx.x * 256 + threadIdx.x;
    if (e >= e_total) return;
    int d = ei[e_total + e];
    atomicAdd(&degi[d], 1);
}

__global__ __launch_bounds__(256) void calc_dis(const int* __restrict__ degi, float* __restrict__ dis, int n) {
    int i = blockIdx.x * 256 + threadIdx.x;
    if (i < n) dis[i] = rsqrtf((float)(degi[i] + 1));   // +1 self loop
}

// inclusive scan per 256-chunk; offs[idx+1] = local inclusive, partials[b] = chunk sum
__global__ __launch_bounds__(256) void scanA(const int* __restrict__ degi, int* __restrict__ offs,
                                             int* __restrict__ partials, int n) {
    __shared__ int sm[256];
    int t = threadIdx.x, idx = blockIdx.x * 256 + t;
    int v = (idx < n) ? degi[idx] : 0;
    sm[t] = v; __syncthreads();
    for (int d = 1; d < 256; d <<= 1) {
        int add = (t >= d) ? sm[t - d] : 0;
        __syncthreads();
        sm[t] += add;
        __syncthreads();
    }
    if (idx < n) offs[idx + 1] = sm[t];
    if (t == 255) partials[blockIdx.x] = sm[255];
}

// exclusive scan of partials (nb <= 256), single block
__global__ __launch_bounds__(256) void scanB(int* __restrict__ partials, int nb) {
    __shared__ int sm[256];
    int t = threadIdx.x;
    int v = (t < nb) ? partials[t] : 0;
    sm[t] = v; __syncthreads();
    for (int d = 1; d < 256; d <<= 1) {
        int add = (t >= d) ? sm[t - d] : 0;
        __syncthreads();
        sm[t] += add;
        __syncthreads();
    }
    if (t < nb) partials[t] = sm[t] - v;   // exclusive
}

__global__ __launch_bounds__(256) void scanC(int* __restrict__ offs, const int* __restrict__ partials, int n) {
    int idx = blockIdx.x * 256 + threadIdx.x;
    if (idx < n) offs[idx + 1] += partials[blockIdx.x];
    if (idx == 0) offs[0] = 0;
}

__global__ __launch_bounds__(256) void copy_i32(const int* __restrict__ a, int* __restrict__ b, int n) {
    int i = blockIdx.x * 256 + threadIdx.x;
    if (i < n) b[i] = a[i];
}

__global__ __launch_bounds__(256) void fill_csr(const int* __restrict__ ei, const float* __restrict__ dis,
                                                int* __restrict__ curs, int* __restrict__ csr_src,
                                                float* __restrict__ csr_w, int e_total) {
    int e = blockIdx.x * 256 + threadIdx.x;
    if (e >= e_total) return;
    int s = ei[e];
    int d = ei[e_total + e];
    int pos = atomicAdd(&curs[d], 1);
    csr_src[pos] = s;
    csr_w[pos] = dis[s] * dis[d];
}

// ---------------- SGEMM: C = A[M,K] @ B[K,N] (+bias, relu) ----------------
// 64x64 tile, BK=16, 256 threads, 4x4 microtile.
__global__ __launch_bounds__(256) void sgemm(const float* __restrict__ A, const float* __restrict__ B,
                                             float* __restrict__ C, const float* __restrict__ bias,
                                             int M, int Nn, int K, int do_relu) {
    __shared__ float As[16][68];   // [k][m], +4 pad
    __shared__ float Bs[16][68];   // [k][n], +4 pad
    int tid = threadIdx.x;
    int tx = tid & 15, ty = tid >> 4;
    int row0 = blockIdx.y * 64, col0 = blockIdx.x * 64;
    int arow = tid >> 2, ac4 = (tid & 3) * 4;
    int brow = tid >> 4, bc4 = (tid & 15) * 4;
    float c[4][4] = {};
    for (int k0 = 0; k0 < K; k0 += 16) {
        float4 av = make_float4(0.f, 0.f, 0.f, 0.f);
        if (row0 + arow < M)
            av = *(const float4*)(A + (size_t)(row0 + arow) * K + k0 + ac4);
        As[ac4 + 0][arow] = av.x;
        As[ac4 + 1][arow] = av.y;
        As[ac4 + 2][arow] = av.z;
        As[ac4 + 3][arow] = av.w;
        float4 bv = *(const float4*)(B + (size_t)(k0 + brow) * Nn + col0 + bc4);
        *(float4*)&Bs[brow][bc4] = bv;
        __syncthreads();
        #pragma unroll
        for (int kk = 0; kk < 16; ++kk) {
            float4 a = *(float4*)&As[kk][ty * 4];
            float4 b = *(float4*)&Bs[kk][tx * 4];
            c[0][0] += a.x * b.x; c[0][1] += a.x * b.y; c[0][2] += a.x * b.z; c[0][3] += a.x * b.w;
            c[1][0] += a.y * b.x; c[1][1] += a.y * b.y; c[1][2] += a.y * b.z; c[1][3] += a.y * b.w;
            c[2][0] += a.z * b.x; c[2][1] += a.z * b.y; c[2][2] += a.z * b.z; c[2][3] += a.z * b.w;
            c[3][0] += a.w * b.x; c[3][1] += a.w * b.y; c[3][2] += a.w * b.z; c[3][3] += a.w * b.w;
        }
        __syncthreads();
    }
    #pragma unroll
    for (int i = 0; i < 4; ++i) {
        int row = row0 + ty * 4 + i;
        if (row >= M) continue;
        #pragma unroll
        for (int j = 0; j < 4; ++j) {
            int col = col0 + tx * 4 + j;
            float v = c[i][j];
            if (bias) v += bias[col];
            if (do_relu) v = v > 0.f ? v : 0.f;
            C[(size_t)row * Nn + col] = v;
        }
    }
}

// ---------------- aggregation: one wave per node, F=256, no bias/relu ----------------
// y[v] = sum_{s->v} x[s]*w + x[v]*dis[v]^2   (pure normalized-adjacency apply;
// bias+relu live in the following sgemm epilogue — agg-first reorder:
// A_norm @ (x W) == (A_norm @ x) W)
__global__ __launch_bounds__(256) void agg256(const float* __restrict__ x, float* __restrict__ y,
                                              const float* __restrict__ dis,
                                              const int* __restrict__ offs, const int* __restrict__ csr_src,
                                              const float* __restrict__ csr_w) {
    constexpr int F = 256;
    constexpr int UNROLL = 8;
    int wave = threadIdx.x >> 6;
    int lane = threadIdx.x & 63;
    int v = __builtin_amdgcn_readfirstlane(blockIdx.x * 4 + wave);
    if (v >= NNODES) return;
    int beg = __builtin_amdgcn_readfirstlane(offs[v]);
    int end = __builtin_amdgcn_readfirstlane(offs[v + 1]);
    float dv = dis[v];
    float selfw = dv * dv;

    const float4* xv = (const float4*)(x + (size_t)v * F);
    float4 a = xv[lane];
    float4 acc = make_float4(a.x * selfw, a.y * selfw, a.z * selfw, a.w * selfw);

    int i = beg;
    for (; i + UNROLL <= end; i += UNROLL) {
        int   s[UNROLL];
        float w[UNROLL];
        #pragma unroll
        for (int u = 0; u < UNROLL; ++u) { s[u] = csr_src[i + u]; w[u] = csr_w[i + u]; }
        float4 g[UNROLL];
        #pragma unroll
        for (int u = 0; u < UNROLL; ++u)
            g[u] = ((const float4*)(x + (size_t)s[u] * F))[lane];
        #pragma unroll
        for (int u = 0; u < UNROLL; ++u) {
            acc.x += g[u].x * w[u]; acc.y += g[u].y * w[u];
            acc.z += g[u].z * w[u]; acc.w += g[u].w * w[u];
        }
    }
    for (; i + 2 <= end; i += 2) {
        int s0 = csr_src[i], s1 = csr_src[i + 1];
        float w0 = csr_w[i], w1 = csr_w[i + 1];
        float4 x0 = ((const float4*)(x + (size_t)s0 * F))[lane];
        float4 x1 = ((const float4*)(x + (size_t)s1 * F))[lane];
        acc.x += x0.x * w0 + x1.x * w1; acc.y += x0.y * w0 + x1.y * w1;
        acc.z += x0.z * w0 + x1.z * w1; acc.w += x0.w * w0 + x1.w * w1;
    }
    if (i < end) {
        int s0 = csr_src[i];
        float w0 = csr_w[i];
        float4 x0 = ((const float4*)(x + (size_t)s0 * F))[lane];
        acc.x += x0.x * w0; acc.y += x0.y * w0; acc.z += x0.z * w0; acc.w += x0.w * w0;
    }

    ((float4*)(y + (size_t)v * F))[lane] = acc;
}

// ---------------- gate: wgate[n] = sigmoid(x[n,:512] . pw + pb) ----------------
__global__ __launch_bounds__(256) void gate(const float* __restrict__ x, const float* __restrict__ pw,
                                            const float* __restrict__ pb, float* __restrict__ wgate, int n) {
    int wid = (blockIdx.x * 256 + threadIdx.x) >> 6;
    int lane = threadIdx.x & 63;
    if (wid >= n) return;
    const float4* xr = (const float4*)(x + (size_t)wid * 512);
    const float4* pwv = (const float4*)pw;
    float4 a = xr[lane], b = pwv[lane];
    float4 a1 = xr[lane + 64], b1 = pwv[lane + 64];
    float acc = a.x * b.x + a.y * b.y + a.z * b.z + a.w * b.w
              + a1.x * b1.x + a1.y * b1.y + a1.z * b1.z + a1.w * b1.w;
    #pragma unroll
    for (int off = 32; off; off >>= 1) acc += __shfl_down(acc, off, 64);
    if (lane == 0) wgate[wid] = 1.f / (1.f + expf(-(acc + pb[0])));
}

// ---------------- pool: pooled[g] = [weighted_sum(512) | max(512)] ----------------
__global__ __launch_bounds__(256) void pool(const float* __restrict__ x, const float* __restrict__ wg,
                                            const int* __restrict__ batch, float* __restrict__ pooled, int n) {
    int g = blockIdx.x;
    int t = threadIdx.x;
    int lo = 0, hi = n;
    while (lo < hi) { int mid = (lo + hi) >> 1; if (batch[mid] < g) lo = mid + 1; else hi = mid; }
    int start = lo;
    hi = n;
    while (lo < hi) { int mid = (lo + hi) >> 1; if (batch[mid] < g + 1) lo = mid + 1; else hi = mid; }
    int end = lo;
    float s0 = 0.f, s1 = 0.f, m0 = -INFINITY, m1 = -INFINITY;
    for (int nn = start; nn < end; ++nn) {
        float wn = wg[nn];
        const float* xr = x + (size_t)nn * 512;
        float v0 = xr[t], v1 = xr[t + 256];
        s0 += v0 * wn; s1 += v1 * wn;
        m0 = fmaxf(m0, v0); m1 = fmaxf(m1, v1);
    }
    if (start >= end) { m0 = 0.f; m1 = 0.f; }
    float* pg = pooled + (size_t)g * 1024;
    pg[t] = s0; pg[t + 256] = s1;
    pg[512 + t] = m0; pg[768 + t] = m1;
}

// ---------------- launch ----------------

extern "C" void kernel_launch(void* const* d_in, const int* in_sizes, int n_in,
                              void* d_out, int out_size, void* d_ws, size_t ws_size,
                              hipStream_t stream) {
    const float* x0    = (const float*)d_in[0];
    const int*   ei    = (const int*)d_in[1];
    const int*   batch = (const int*)d_in[2];
    const float* W1 = (const float*)d_in[3];
    const float* b1 = (const float*)d_in[4];
    const float* W2 = (const float*)d_in[5];
    const float* b2 = (const float*)d_in[6];
    const float* W3 = (const float*)d_in[7];
    const float* b3 = (const float*)d_in[8];
    const float* pw = (const float*)d_in[9];
    const float* pb = (const float*)d_in[10];
    const float* Wo = (const float*)d_in[11];
    const float* bo = (const float*)d_in[12];
    float* out = (float*)d_out;

    // workspace layout (4B words, each region 16B-aligned)
    float* ws = (float*)d_ws;
    size_t off = 0;
    float* bufA = ws + off; off += (size_t)NNODES * 512;   // agg outputs (256-wide) / scratch
    float* bufB = ws + off; off += (size_t)NNODES * 512;   // layer outputs (x1,x2 256-wide; x3 512-wide)
    float* dis  = ws + off; off += NNODES;
    int*   degi = (int*)(ws + off); off += NNODES;
    int*   offs = (int*)(ws + off); off += (NNODES + 4);
    int*   curs = (int*)(ws + off); off += NNODES;
    int*   csr_src = (int*)(ws + off); off += NEDGES;
    float* csr_w   = ws + off; off += NEDGES;
    float* wgate   = ws + off; off += NNODES;
    float* pooled  = ws + off; off += (size_t)NGRAPH * 1024;
    int*   partials = (int*)(ws + off); off += 256;

    const int NB_N = (NNODES + 255) / 256;   // 196
    const int NB_E = (NEDGES + 255) / 256;
    const int NB_W = (NNODES + 3) / 4;       // one wave per node, 4 waves/block (12500)

    // CSR build
    zero_i32<<<NB_N, 256, 0, stream>>>(degi, NNODES);
    count_deg<<<NB_E, 256, 0, stream>>>(ei, degi, NEDGES);
    calc_dis<<<NB_N, 256, 0, stream>>>(degi, dis, NNODES);
    scanA<<<NB_N, 256, 0, stream>>>(degi, offs, partials, NNODES);
    scanB<<<1, 256, 0, stream>>>(partials, NB_N);
    scanC<<<NB_N, 256, 0, stream>>>(offs, partials, NNODES);
    copy_i32<<<NB_N, 256, 0, stream>>>(offs, curs, NNODES);
    fill_csr<<<NB_E, 256, 0, stream>>>(ei, dis, curs, csr_src, csr_w, NEDGES);

    // layer 1: y = A_norm @ x0 ; x1 = relu(y @ W1 + b1)
    agg256<<<NB_W, 256, 0, stream>>>(x0, bufA, dis, offs, csr_src, csr_w);
    {
        dim3 grid(H1 / 64, (NNODES + 63) / 64);
        sgemm<<<grid, 256, 0, stream>>>(bufA, W1, bufB, b1, NNODES, H1, FIN, 1);
    }
    // layer 2: y = A_norm @ x1 ; x2 = relu(y @ W2 + b2)
    agg256<<<NB_W, 256, 0, stream>>>(bufB, bufA, dis, offs, csr_src, csr_w);
    {
        dim3 grid(H2 / 64, (NNODES + 63) / 64);
        sgemm<<<grid, 256, 0, stream>>>(bufA, W2, bufB, b2, NNODES, H2, H1, 1);
    }
    // layer 3: y = A_norm @ x2 (256-wide!) ; x3 = relu(y @ W3 + b3)  [512-wide out]
    agg256<<<NB_W, 256, 0, stream>>>(bufB, bufA, dis, offs, csr_src, csr_w);
    {
        dim3 grid(H3 / 64, (NNODES + 63) / 64);
        sgemm<<<grid, 256, 0, stream>>>(bufA, W3, bufB, b3, NNODES, H3, H2, 1);
    }
    // gate + pool
    gate<<<(NNODES * 64 + 255) / 256, 256, 0, stream>>>(bufB, pw, pb, wgate, NNODES);
    pool<<<NGRAPH, 256, 0, stream>>>(bufB, wgate, batch, pooled, NNODES);
    // head: out = relu(pooled @ Wo + bo)
    {
        dim3 grid(FPOUT / 64, NGRAPH / 64);
        sgemm<<<grid, 256, 0, stream>>>(pooled, Wo, out, bo, NGRAPH, FPOUT, 2 * H3, 1);
    }
}